// Round 7
// baseline (79.080 us; speedup 1.0000x reference)
//
#include <hip/hip_runtime.h>
#include <hip/hip_fp16.h>

// VoxelProjection_fish — two-phase:
//  (A) transpose input [C][P] f32 -> T2 [P][384] f16 (padded rows: 6 chunks of 56ch
//      at 64-half offsets -> every chunk read starts 128B-aligned)
//  (B) per-voxel gather (8B granules) w/ register prefetch + LDS transpose + NT store.
//      VB=128 -> 512B write runs per channel-row.

#define C_IN  336
#define ZB    6
#define BEV_H 240
#define BEV_W 120
#define LVOX  (ZB * BEV_H * BEV_W)   // 172800
#define HF    160
#define WF    256
#define PIX   (HF * WF)              // 40960
#define HW    (BEV_H * BEV_W)        // 28800

#define CC    56                     // channels per chunk
#define NCH   (C_IN / CC)            // 6
#define CHH   64                     // half-offset stride between chunks (128 B)
#define ROWH  (NCH * CHH)            // 384 halves per row (768 B)

typedef float f32x4 __attribute__((ext_vector_type(4)));   // NT-store-compatible

// ---------- Kernel A: transpose input [C_IN][PIX] f32 -> T2 [PIX][ROWH] f16 ----------
#define TA_P 64
#define TA_C 48   // 336 = 7 * 48
__global__ __launch_bounds__(256) void transpose_f16_kernel(
    const float* __restrict__ in, __half* __restrict__ T2)
{
    __shared__ float tile[TA_C][TA_P + 1];
    const int p0 = blockIdx.x * TA_P;
    const int c0 = blockIdx.y * TA_C;
    const int t  = threadIdx.x;

    #pragma unroll
    for (int i = 0; i < (TA_P * TA_C) / 256; ++i) {   // 12
        int idx = i * 256 + t;
        int cl = idx >> 6;
        int pl = idx & 63;
        tile[cl][pl] = __builtin_nontemporal_load(
            &in[(size_t)(c0 + cl) * PIX + p0 + pl]);   // coalesced 256B rows, read-once
    }
    __syncthreads();
    #pragma unroll
    for (int i = 0; i < (TA_P * TA_C / 2) / 256; ++i) {   // 6: one half2 per thread
        int idx = i * 256 + t;
        int cl2 = idx % (TA_C / 2);
        int pl  = idx / (TA_C / 2);
        int c   = c0 + 2 * cl2;            // even; 56 even -> pair never straddles a chunk
        int chunk = c / CC;
        int poff  = chunk * CHH + (c - chunk * CC);
        __half2 hv = __floats2half2_rn(tile[2 * cl2][pl], tile[2 * cl2 + 1][pl]);
        *reinterpret_cast<__half2*>(&T2[(size_t)(p0 + pl) * ROWH + poff]) = hv;
    }
}

// ---------- Kernel B: gather fp16 rows, weight, LDS transpose, NT store ----------
#define VB   128               // voxels per block (128 | 28800 -> z uniform, 225 blocks/z)
#define LROW (VB + 1)          // 129 floats
#define GPV  (CC / 4)          // 14 uint2 granules (4ch) per voxel-chunk
#define NG   ((VB * GPV) / 256)  // 7 granules per thread, exact split

__global__ __launch_bounds__(256) void gather_f16_kernel(
    const __half* __restrict__ T2,
    const int*    __restrict__ uu,
    const int*    __restrict__ vv,
    const float*  __restrict__ valid,
    const float*  __restrict__ density,
    float*        __restrict__ out)
{
    __shared__ float tile[CC * LROW];   // 28.9 KB -> 5 blocks/CU
    __shared__ int   p_s[VB];
    __shared__ float w_s[VB];

    const int t   = threadIdx.x;
    const int l0  = blockIdx.x * VB;
    const int z   = l0 / HW;            // wave-uniform
    const int hw0 = l0 - z * HW;

    if (t < VB) {
        int l = l0 + t;
        p_s[t] = vv[l] * WF + uu[l];
        w_s[t] = valid[l] * density[l];
    }
    __syncthreads();

    // Fixed per-thread (voxel, granule) assignment; pixels/weights into regs.
    int   vi[NG], gi[NG];
    float myw[NG];
    const __half* qbase[NG];
    #pragma unroll
    for (int i = 0; i < NG; ++i) {
        int idx = i * 256 + t;
        vi[i] = idx / GPV;
        gi[i] = idx - vi[i] * GPV;
        myw[i] = w_s[vi[i]];
        qbase[i] = T2 + (size_t)p_s[vi[i]] * ROWH + gi[i] * 4;   // 8B-aligned
    }

    // Prefetch chunk 0 into regs.
    uint2 pf[NG];
    #pragma unroll
    for (int i = 0; i < NG; ++i)
        pf[i] = *reinterpret_cast<const uint2*>(qbase[i]);

    #pragma unroll
    for (int ch = 0; ch < NCH; ++ch) {
        // Unpack + weight -> LDS [c][v]
        #pragma unroll
        for (int i = 0; i < NG; ++i) {
            const float2 f01 = __half22float2(*reinterpret_cast<const __half2*>(&pf[i].x));
            const float2 f23 = __half22float2(*reinterpret_cast<const __half2*>(&pf[i].y));
            const float w = myw[i];
            int base = (gi[i] * 4) * LROW + vi[i];
            tile[base]          = f01.x * w;
            tile[base + LROW]   = f01.y * w;
            tile[base + 2*LROW] = f23.x * w;
            tile[base + 3*LROW] = f23.y * w;
        }
        __syncthreads();

        // T14: issue next chunk's gathers now; in flight through the store phase.
        if (ch + 1 < NCH) {
            #pragma unroll
            for (int i = 0; i < NG; ++i)
                pf[i] = *reinterpret_cast<const uint2*>(qbase[i] + (ch + 1) * CHH);
        }

        // Store phase: per channel-row, 32 lanes x f32x4 = 512B runs, NT coalesced.
        {
            const int vq = (t & 31) * 4;
            const int cb = t >> 5;                // 0..7
            #pragma unroll
            for (int i2 = 0; i2 < CC / 8; ++i2) { // 7
                int cl = i2 * 8 + cb;
                f32x4 o;
                o.x = tile[cl * LROW + vq + 0];
                o.y = tile[cl * LROW + vq + 1];
                o.z = tile[cl * LROW + vq + 2];
                o.w = tile[cl * LROW + vq + 3];
                __builtin_nontemporal_store(o, reinterpret_cast<f32x4*>(
                    &out[(size_t)(z * C_IN + ch * CC + cl) * HW + hw0 + vq]));
            }
        }
        __syncthreads();
    }
}

// ---------- Fallback: direct scattered gather (round-1 kernel) ----------
#define CPT 16
__global__ __launch_bounds__(256) void voxel_proj_direct(
    const float* __restrict__ input,
    const int*   __restrict__ uu,
    const int*   __restrict__ vv,
    const float* __restrict__ valid,
    const float* __restrict__ density,
    float*       __restrict__ out)
{
    const int l = blockIdx.x * 256 + threadIdx.x;
    const int p = vv[l] * WF + uu[l];
    const float w = valid[l] * density[l];
    const int z  = l / HW;
    const int hw = l - z * HW;
    const float* inb  = input + p;
    float*       outb = out + (size_t)z * C_IN * HW + hw;
    const int c0 = blockIdx.y * CPT;
    #pragma unroll
    for (int i = 0; i < CPT; ++i) {
        const int c = c0 + i;
        outb[(size_t)c * HW] = inb[(size_t)c * PIX] * w;
    }
}

extern "C" void kernel_launch(void* const* d_in, const int* in_sizes, int n_in,
                              void* d_out, int out_size, void* d_ws, size_t ws_size,
                              hipStream_t stream)
{
    const float* input   = (const float*)d_in[0];
    const int*   uu      = (const int*)  d_in[1];
    const int*   vv      = (const int*)  d_in[2];
    const float* valid   = (const float*)d_in[3];
    const float* density = (const float*)d_in[4];
    float*       out     = (float*)d_out;

    const size_t T_bytes = (size_t)PIX * ROWH * sizeof(__half);   // 31.5 MB
    if (ws_size >= T_bytes) {
        __half* T2 = (__half*)d_ws;
        transpose_f16_kernel<<<dim3(PIX / TA_P, C_IN / TA_C), dim3(256), 0, stream>>>(input, T2);
        gather_f16_kernel<<<dim3(LVOX / VB), dim3(256), 0, stream>>>(T2, uu, vv, valid, density, out);
    } else {
        voxel_proj_direct<<<dim3(LVOX / 256, C_IN / CPT), dim3(256), 0, stream>>>(
            input, uu, vv, valid, density, out);
    }
}

// Round 8
// 75.933 us; speedup vs baseline: 1.0414x; 1.0414x over previous
//
#include <hip/hip_runtime.h>
#include <hip/hip_fp16.h>

// VoxelProjection_fish — two-phase:
//  (A) transpose input [C][P] f32 -> T2 [P][384] f16 (3 chunks of 112ch at 128-half
//      offsets -> every 224B chunk read starts 256B-aligned)
//  (B) per-voxel gather (8B granules) w/ register prefetch; weighted product kept as
//      __half2 in LDS (conflict-free writes, half the LDS traffic); NT f32 stores.

#define C_IN  336
#define ZB    6
#define BEV_H 240
#define BEV_W 120
#define LVOX  (ZB * BEV_H * BEV_W)   // 172800
#define HF    160
#define WF    256
#define PIX   (HF * WF)              // 40960
#define HW    (BEV_H * BEV_W)        // 28800

#define CC    112                    // channels per chunk
#define NCH   (C_IN / CC)            // 3
#define CHH   128                    // half-offset stride between chunks (256 B)
#define ROWH  (NCH * CHH)            // 384 halves per row (768 B)

typedef float f32x4 __attribute__((ext_vector_type(4)));   // NT-store-compatible

// ---------- Kernel A: transpose input [C_IN][PIX] f32 -> T2 [PIX][ROWH] f16 ----------
#define TA_P 64
#define TA_C 48   // 336 = 7 * 48
__global__ __launch_bounds__(256) void transpose_f16_kernel(
    const float* __restrict__ in, __half* __restrict__ T2)
{
    __shared__ float tile[TA_C][TA_P + 1];
    const int p0 = blockIdx.x * TA_P;
    const int c0 = blockIdx.y * TA_C;
    const int t  = threadIdx.x;

    #pragma unroll
    for (int i = 0; i < (TA_P * TA_C) / 256; ++i) {   // 12
        int idx = i * 256 + t;
        int cl = idx >> 6;
        int pl = idx & 63;
        tile[cl][pl] = __builtin_nontemporal_load(
            &in[(size_t)(c0 + cl) * PIX + p0 + pl]);   // coalesced 256B rows, read-once
    }
    __syncthreads();
    #pragma unroll
    for (int i = 0; i < (TA_P * TA_C / 2) / 256; ++i) {   // 6: one half2 per thread
        int idx = i * 256 + t;
        int cl2 = idx % (TA_C / 2);
        int pl  = idx / (TA_C / 2);
        int c   = c0 + 2 * cl2;            // even; pairs never straddle 112-boundaries
        int chunk = c / CC;
        int poff  = chunk * CHH + (c - chunk * CC);
        __half2 hv = __floats2half2_rn(tile[2 * cl2][pl], tile[2 * cl2 + 1][pl]);
        *reinterpret_cast<__half2*>(&T2[(size_t)(p0 + pl) * ROWH + poff]) = hv;
    }
}

// ---------- Kernel B: gather fp16, weight in fp16, LDS half2 transpose, NT store ----------
#define VB   64                // voxels per block (64 | 28800 -> z uniform)
#define LROW 65                // b32 (=half2) row length: 2-way max on writes/reads (free)
#define NROW (CC / 2)          // 56 half2-rows per chunk (row r holds channels 2r, 2r+1)
#define GPV  (CC / 4)          // 28 uint2 granules (4ch) per voxel-chunk
#define NG   ((VB * GPV) / 256)  // 7 granules per thread, exact

__global__ __launch_bounds__(256) void gather_f16_kernel(
    const __half* __restrict__ T2,
    const int*    __restrict__ uu,
    const int*    __restrict__ vv,
    const float*  __restrict__ valid,
    const float*  __restrict__ density,
    float*        __restrict__ out)
{
    __shared__ __half2 tile[NROW * LROW];   // 14.2 KB -> 8 blocks/CU (wave-capped)
    __shared__ int   p_s[VB];
    __shared__ float w_s[VB];

    const int t   = threadIdx.x;
    const int l0  = blockIdx.x * VB;
    const int z   = l0 / HW;            // wave-uniform
    const int hw0 = l0 - z * HW;

    if (t < VB) {
        int l = l0 + t;
        p_s[t] = vv[l] * WF + uu[l];
        w_s[t] = valid[l] * density[l];
    }
    __syncthreads();

    // Fixed per-thread (voxel, granule) assignment; weights as splatted half2.
    int     vi[NG], gi[NG];
    __half2 wh[NG];
    const __half* qbase[NG];
    #pragma unroll
    for (int i = 0; i < NG; ++i) {
        int idx = i * 256 + t;
        vi[i] = idx / GPV;
        gi[i] = idx - vi[i] * GPV;
        wh[i] = __float2half2_rn(w_s[vi[i]]);
        qbase[i] = T2 + (size_t)p_s[vi[i]] * ROWH + gi[i] * 4;   // 8B-aligned
    }

    // Prefetch chunk 0 into regs.
    uint2 pf[NG];
    #pragma unroll
    for (int i = 0; i < NG; ++i)
        pf[i] = *reinterpret_cast<const uint2*>(qbase[i]);

    #pragma unroll
    for (int ch = 0; ch < NCH; ++ch) {
        // Weight in fp16 (2 pk-muls) -> 2 conflict-free LDS b32 writes per granule.
        // Row 2g+jp banks: (2g+jp+v) mod 32 -> 16 banks over the 28-lane v-group (<=2-way).
        #pragma unroll
        for (int i = 0; i < NG; ++i) {
            const __half2 h01 = __hmul2(*reinterpret_cast<const __half2*>(&pf[i].x), wh[i]);
            const __half2 h23 = __hmul2(*reinterpret_cast<const __half2*>(&pf[i].y), wh[i]);
            int base = (2 * gi[i]) * LROW + vi[i];
            tile[base]        = h01;
            tile[base + LROW] = h23;
        }
        __syncthreads();

        // T14: issue next chunk's gathers; in flight through the store phase.
        if (ch + 1 < NCH) {
            #pragma unroll
            for (int i = 0; i < NG; ++i)
                pf[i] = *reinterpret_cast<const uint2*>(qbase[i] + (ch + 1) * CHH);
        }

        // Store phase: per channel-row, 16 lanes x f32x4 = 256B coalesced NT stores.
        // Row cl>>1 holds channels (cl&1 selects half); broadcast pairs + 2-way = free.
        {
            const int vq  = (t & 15) * 4;
            const int cb  = t >> 4;          // 0..15
            const int sel = cb & 1;          // channel parity, uniform over i2
            #pragma unroll
            for (int i2 = 0; i2 < CC / 16; ++i2) {   // 7
                int cl  = i2 * 16 + cb;
                int row = cl >> 1;
                f32x4 o;
                #pragma unroll
                for (int j = 0; j < 4; ++j) {
                    float2 f2 = __half22float2(tile[row * LROW + vq + j]);
                    o[j] = sel ? f2.y : f2.x;
                }
                __builtin_nontemporal_store(o, reinterpret_cast<f32x4*>(
                    &out[(size_t)(z * C_IN + ch * CC + cl) * HW + hw0 + vq]));
            }
        }
        __syncthreads();
    }
}

// ---------- Fallback: direct scattered gather (round-1 kernel) ----------
#define CPT 16
__global__ __launch_bounds__(256) void voxel_proj_direct(
    const float* __restrict__ input,
    const int*   __restrict__ uu,
    const int*   __restrict__ vv,
    const float* __restrict__ valid,
    const float* __restrict__ density,
    float*       __restrict__ out)
{
    const int l = blockIdx.x * 256 + threadIdx.x;
    const int p = vv[l] * WF + uu[l];
    const float w = valid[l] * density[l];
    const int z  = l / HW;
    const int hw = l - z * HW;
    const float* inb  = input + p;
    float*       outb = out + (size_t)z * C_IN * HW + hw;
    const int c0 = blockIdx.y * CPT;
    #pragma unroll
    for (int i = 0; i < CPT; ++i) {
        const int c = c0 + i;
        outb[(size_t)c * HW] = inb[(size_t)c * PIX] * w;
    }
}

extern "C" void kernel_launch(void* const* d_in, const int* in_sizes, int n_in,
                              void* d_out, int out_size, void* d_ws, size_t ws_size,
                              hipStream_t stream)
{
    const float* input   = (const float*)d_in[0];
    const int*   uu      = (const int*)  d_in[1];
    const int*   vv      = (const int*)  d_in[2];
    const float* valid   = (const float*)d_in[3];
    const float* density = (const float*)d_in[4];
    float*       out     = (float*)d_out;

    const size_t T_bytes = (size_t)PIX * ROWH * sizeof(__half);   // 31.5 MB
    if (ws_size >= T_bytes) {
        __half* T2 = (__half*)d_ws;
        transpose_f16_kernel<<<dim3(PIX / TA_P, C_IN / TA_C), dim3(256), 0, stream>>>(input, T2);
        gather_f16_kernel<<<dim3(LVOX / VB), dim3(256), 0, stream>>>(T2, uu, vv, valid, density, out);
    } else {
        voxel_proj_direct<<<dim3(LVOX / 256, C_IN / CPT), dim3(256), 0, stream>>>(
            input, uu, vv, valid, density, out);
    }
}

// Round 9
// 75.820 us; speedup vs baseline: 1.0430x; 1.0015x over previous
//
#include <hip/hip_runtime.h>
#include <hip/hip_fp16.h>

// VoxelProjection_fish — two-phase (round-5 structure, unpadded T2 rows):
//  (A) transpose input [C][P] f32 -> T2 [P][336] f16 (672B rows, 8B-aligned everywhere)
//  (B) per-voxel gather (8B granules) w/ register prefetch + LDS transpose + NT store.

#define C_IN  336
#define ZB    6
#define BEV_H 240
#define BEV_W 120
#define LVOX  (ZB * BEV_H * BEV_W)   // 172800
#define HF    160
#define WF    256
#define PIX   (HF * WF)              // 40960
#define HW    (BEV_H * BEV_W)        // 28800

#define CC    112                    // channels per chunk (336 = 3 * 112)
#define NCH   (C_IN / CC)            // 3
#define CHH   CC                     // half-offset stride between chunks (224 B, unpadded)
#define ROWH  C_IN                   // 336 halves per row (672 B = 84*8 -> 8B-aligned rows)

typedef float f32x4 __attribute__((ext_vector_type(4)));   // NT-store-compatible

// ---------- Kernel A: transpose input [C_IN][PIX] f32 -> T2 [PIX][ROWH] f16 ----------
#define TA_P 64
#define TA_C 48   // 336 = 7 * 48
__global__ __launch_bounds__(256) void transpose_f16_kernel(
    const float* __restrict__ in, __half* __restrict__ T2)
{
    __shared__ float tile[TA_C][TA_P + 1];
    const int p0 = blockIdx.x * TA_P;
    const int c0 = blockIdx.y * TA_C;
    const int t  = threadIdx.x;

    #pragma unroll
    for (int i = 0; i < (TA_P * TA_C) / 256; ++i) {   // 12
        int idx = i * 256 + t;
        int cl = idx >> 6;
        int pl = idx & 63;
        tile[cl][pl] = __builtin_nontemporal_load(
            &in[(size_t)(c0 + cl) * PIX + p0 + pl]);   // coalesced 256B rows, read-once
    }
    __syncthreads();
    #pragma unroll
    for (int i = 0; i < (TA_P * TA_C / 2) / 256; ++i) {   // 6: one half2 per thread
        int idx = i * 256 + t;
        int cl2 = idx % (TA_C / 2);     // 0..23
        int pl  = idx / (TA_C / 2);
        __half2 hv = __floats2half2_rn(tile[2 * cl2][pl], tile[2 * cl2 + 1][pl]);
        *reinterpret_cast<__half2*>(
            &T2[(size_t)(p0 + pl) * ROWH + c0 + 2 * cl2]) = hv;   // 96B runs per 24 lanes
    }
}

// ---------- Kernel B: gather fp16 rows, weight, LDS transpose, NT store ----------
#define VB   64                // voxels per block (64 | 28800 -> z uniform)
#define LROW (VB + 1)          // 65 floats: phase-3 reads 2-way max (free)
#define NGPV (CC / 4)          // 28 uint2 granules per voxel-chunk
#define NG   ((VB * NGPV) / 256)  // 7 granules per thread, exact

__global__ __launch_bounds__(256) void gather_f16_kernel(
    const __half* __restrict__ T2,
    const int*    __restrict__ uu,
    const int*    __restrict__ vv,
    const float*  __restrict__ valid,
    const float*  __restrict__ density,
    float*        __restrict__ out)
{
    __shared__ float tile[CC * LROW];   // 29.1 KB -> 5 blocks/CU
    __shared__ int   p_s[VB];
    __shared__ float w_s[VB];

    const int t   = threadIdx.x;
    const int l0  = blockIdx.x * VB;
    const int z   = l0 / HW;            // wave-uniform
    const int hw0 = l0 - z * HW;

    if (t < VB) {
        int l = l0 + t;
        p_s[t] = vv[l] * WF + uu[l];
        w_s[t] = valid[l] * density[l];
    }
    __syncthreads();

    // Per-thread fixed (voxel, granule) assignment; weights/pixels into regs.
    int   vi[NG], gi[NG], myp[NG];
    float myw[NG];
    #pragma unroll
    for (int i = 0; i < NG; ++i) {
        int idx = i * 256 + t;
        vi[i]  = idx / NGPV;
        gi[i]  = idx - vi[i] * NGPV;
        myp[i] = p_s[vi[i]];
        myw[i] = w_s[vi[i]];
    }

    // Prefetch chunk 0 into regs (8B scattered loads; 672p + 8g -> 8B-aligned).
    uint2 pf[NG];
    #pragma unroll
    for (int i = 0; i < NG; ++i)
        pf[i] = *reinterpret_cast<const uint2*>(
            &T2[(size_t)myp[i] * ROWH + gi[i] * 4]);

    #pragma unroll
    for (int ch = 0; ch < NCH; ++ch) {
        // Unpack + weight -> LDS [c][v]
        #pragma unroll
        for (int i = 0; i < NG; ++i) {
            const float2 f01 = __half22float2(*reinterpret_cast<const __half2*>(&pf[i].x));
            const float2 f23 = __half22float2(*reinterpret_cast<const __half2*>(&pf[i].y));
            const float w = myw[i];
            int base = (gi[i] * 4) * LROW + vi[i];
            tile[base]          = f01.x * w;
            tile[base + LROW]   = f01.y * w;
            tile[base + 2*LROW] = f23.x * w;
            tile[base + 3*LROW] = f23.y * w;
        }
        __syncthreads();

        // T14: issue next chunk's gathers now; in flight through the store phase.
        if (ch + 1 < NCH) {
            #pragma unroll
            for (int i = 0; i < NG; ++i)
                pf[i] = *reinterpret_cast<const uint2*>(
                    &T2[(size_t)myp[i] * ROWH + (ch + 1) * CHH + gi[i] * 4]);
        }

        // Store phase: per channel-row, 16 lanes x f32x4 = 256B coalesced NT stores.
        {
            const int vq = (t & 15) * 4;
            const int cb = t >> 4;
            #pragma unroll
            for (int i2 = 0; i2 < CC / 16; ++i2) {   // 7
                int cl = i2 * 16 + cb;
                f32x4 o;
                o.x = tile[cl * LROW + vq + 0];
                o.y = tile[cl * LROW + vq + 1];
                o.z = tile[cl * LROW + vq + 2];
                o.w = tile[cl * LROW + vq + 3];
                __builtin_nontemporal_store(o, reinterpret_cast<f32x4*>(
                    &out[(size_t)(z * C_IN + ch * CC + cl) * HW + hw0 + vq]));
            }
        }
        __syncthreads();
    }
}

// ---------- Fallback: direct scattered gather (round-1 kernel) ----------
#define CPT 16
__global__ __launch_bounds__(256) void voxel_proj_direct(
    const float* __restrict__ input,
    const int*   __restrict__ uu,
    const int*   __restrict__ vv,
    const float* __restrict__ valid,
    const float* __restrict__ density,
    float*       __restrict__ out)
{
    const int l = blockIdx.x * 256 + threadIdx.x;
    const int p = vv[l] * WF + uu[l];
    const float w = valid[l] * density[l];
    const int z  = l / HW;
    const int hw = l - z * HW;
    const float* inb  = input + p;
    float*       outb = out + (size_t)z * C_IN * HW + hw;
    const int c0 = blockIdx.y * CPT;
    #pragma unroll
    for (int i = 0; i < CPT; ++i) {
        const int c = c0 + i;
        outb[(size_t)c * HW] = inb[(size_t)c * PIX] * w;
    }
}

extern "C" void kernel_launch(void* const* d_in, const int* in_sizes, int n_in,
                              void* d_out, int out_size, void* d_ws, size_t ws_size,
                              hipStream_t stream)
{
    const float* input   = (const float*)d_in[0];
    const int*   uu      = (const int*)  d_in[1];
    const int*   vv      = (const int*)  d_in[2];
    const float* valid   = (const float*)d_in[3];
    const float* density = (const float*)d_in[4];
    float*       out     = (float*)d_out;

    const size_t T_bytes = (size_t)PIX * ROWH * sizeof(__half);   // 27.6 MB
    if (ws_size >= T_bytes) {
        __half* T2 = (__half*)d_ws;
        transpose_f16_kernel<<<dim3(PIX / TA_P, C_IN / TA_C), dim3(256), 0, stream>>>(input, T2);
        gather_f16_kernel<<<dim3(LVOX / VB), dim3(256), 0, stream>>>(T2, uu, vv, valid, density, out);
    } else {
        voxel_proj_direct<<<dim3(LVOX / 256, C_IN / CPT), dim3(256), 0, stream>>>(
            input, uu, vv, valid, density, out);
    }
}

// Round 10
// 72.480 us; speedup vs baseline: 1.0911x; 1.0461x over previous
//
#include <hip/hip_runtime.h>
#include <hip/hip_fp16.h>

// VoxelProjection_fish — two-phase (round-5 best config, FINAL):
//  (A) transpose input [C][P] f32 -> T2 [P][384] f16 (padded rows: 3 chunks of 112ch
//      at 128-half offsets -> every 224B chunk read spans exactly 4 aligned 64B lines)
//  (B) per-voxel gather (8B granules) w/ register prefetch + LDS transpose + NT store.
// Measured 72.6 us ≈ 6.2 TB/s combined traffic (451 MB) — at the achievable BW ceiling.

#define C_IN  336
#define ZB    6
#define BEV_H 240
#define BEV_W 120
#define LVOX  (ZB * BEV_H * BEV_W)   // 172800
#define HF    160
#define WF    256
#define PIX   (HF * WF)              // 40960
#define HW    (BEV_H * BEV_W)        // 28800

#define ROWH  384                    // halves per row (768 B)
#define CHH   128                    // half-offset stride between chunks (256 B)

typedef float f32x4 __attribute__((ext_vector_type(4)));   // NT-store-compatible

// ---------- Kernel A: transpose input [C_IN][PIX] f32 -> T2 [PIX][ROWH] f16 ----------
#define TA_P 64
#define TA_C 48   // 336 = 7 * 48
__global__ __launch_bounds__(256) void transpose_f16_kernel(
    const float* __restrict__ in, __half* __restrict__ T2)
{
    __shared__ float tile[TA_C][TA_P + 1];
    const int p0 = blockIdx.x * TA_P;
    const int c0 = blockIdx.y * TA_C;
    const int t  = threadIdx.x;

    #pragma unroll
    for (int i = 0; i < (TA_P * TA_C) / 256; ++i) {   // 12
        int idx = i * 256 + t;
        int cl = idx >> 6;
        int pl = idx & 63;
        tile[cl][pl] = in[(size_t)(c0 + cl) * PIX + p0 + pl];   // coalesced 256B rows
    }
    __syncthreads();
    #pragma unroll
    for (int i = 0; i < (TA_P * TA_C / 2) / 256; ++i) {   // 6: one half2 per thread
        int idx = i * 256 + t;
        int cl2 = idx % (TA_C / 2);
        int pl  = idx / (TA_C / 2);
        int c   = c0 + 2 * cl2;                // even; pairs never straddle 112-boundaries
        int chunk = c / 112;
        int poff  = chunk * CHH + (c - chunk * 112);
        __half2 hv = __floats2half2_rn(tile[2 * cl2][pl], tile[2 * cl2 + 1][pl]);
        *reinterpret_cast<__half2*>(&T2[(size_t)(p0 + pl) * ROWH + poff]) = hv;
    }
}

// ---------- Kernel B: gather fp16 rows, weight, LDS transpose, NT store ----------
#define VB   64                // voxels per block (64 | 28800 -> z uniform)
#define CC   112               // channels per chunk (336 = 3 * 112)
#define NCH  (C_IN / CC)       // 3
#define LROW (VB + 1)          // 65 floats: phase-3 reads 2-way max (free)
#define NGPV (CC / 4)          // 28 uint2 granules per voxel-chunk
#define NG   ((VB * NGPV) / 256)  // 7 granules per thread

__global__ __launch_bounds__(256) void gather_f16_kernel(
    const __half* __restrict__ T2,
    const int*    __restrict__ uu,
    const int*    __restrict__ vv,
    const float*  __restrict__ valid,
    const float*  __restrict__ density,
    float*        __restrict__ out)
{
    __shared__ float tile[CC * LROW];   // 29.1 KB -> 5 blocks/CU
    __shared__ int   p_s[VB];
    __shared__ float w_s[VB];

    const int t   = threadIdx.x;
    const int l0  = blockIdx.x * VB;
    const int z   = l0 / HW;            // wave-uniform
    const int hw0 = l0 - z * HW;

    if (t < VB) {
        int l = l0 + t;
        p_s[t] = vv[l] * WF + uu[l];
        w_s[t] = valid[l] * density[l];
    }
    __syncthreads();

    // Per-thread fixed (voxel, granule) assignment; weights/pixels into regs.
    int   vi[NG], gi[NG], myp[NG];
    float myw[NG];
    #pragma unroll
    for (int i = 0; i < NG; ++i) {
        int idx = i * 256 + t;
        vi[i]  = idx / NGPV;
        gi[i]  = idx - vi[i] * NGPV;
        myp[i] = p_s[vi[i]];
        myw[i] = w_s[vi[i]];
    }

    // Prefetch chunk 0 into regs.
    uint2 pf[NG];
    #pragma unroll
    for (int i = 0; i < NG; ++i)
        pf[i] = *reinterpret_cast<const uint2*>(
            &T2[(size_t)myp[i] * ROWH + gi[i] * 4]);

    #pragma unroll
    for (int ch = 0; ch < NCH; ++ch) {
        // Unpack + weight -> LDS [c][v]
        #pragma unroll
        for (int i = 0; i < NG; ++i) {
            const float2 f01 = __half22float2(*reinterpret_cast<const __half2*>(&pf[i].x));
            const float2 f23 = __half22float2(*reinterpret_cast<const __half2*>(&pf[i].y));
            const float w = myw[i];
            int base = (gi[i] * 4) * LROW + vi[i];
            tile[base]          = f01.x * w;
            tile[base + LROW]   = f01.y * w;
            tile[base + 2*LROW] = f23.x * w;
            tile[base + 3*LROW] = f23.y * w;
        }
        __syncthreads();

        // T14: issue next chunk's gathers now; they stay in flight through the store phase.
        if (ch + 1 < NCH) {
            #pragma unroll
            for (int i = 0; i < NG; ++i)
                pf[i] = *reinterpret_cast<const uint2*>(
                    &T2[(size_t)myp[i] * ROWH + (ch + 1) * CHH + gi[i] * 4]);
        }

        // Store phase: per channel-row, 16 lanes x f32x4 = 256B coalesced NT stores.
        {
            const int vq = (t & 15) * 4;
            const int cb = t >> 4;
            #pragma unroll
            for (int i2 = 0; i2 < CC / 16; ++i2) {   // 7
                int cl = i2 * 16 + cb;
                f32x4 o;
                o.x = tile[cl * LROW + vq + 0];
                o.y = tile[cl * LROW + vq + 1];
                o.z = tile[cl * LROW + vq + 2];
                o.w = tile[cl * LROW + vq + 3];
                __builtin_nontemporal_store(o, reinterpret_cast<f32x4*>(
                    &out[(size_t)(z * C_IN + ch * CC + cl) * HW + hw0 + vq]));
            }
        }
        __syncthreads();
    }
}

// ---------- Fallback: direct scattered gather (round-1 kernel) ----------
#define CPT 16
__global__ __launch_bounds__(256) void voxel_proj_direct(
    const float* __restrict__ input,
    const int*   __restrict__ uu,
    const int*   __restrict__ vv,
    const float* __restrict__ valid,
    const float* __restrict__ density,
    float*       __restrict__ out)
{
    const int l = blockIdx.x * 256 + threadIdx.x;
    const int p = vv[l] * WF + uu[l];
    const float w = valid[l] * density[l];
    const int z  = l / HW;
    const int hw = l - z * HW;
    const float* inb  = input + p;
    float*       outb = out + (size_t)z * C_IN * HW + hw;
    const int c0 = blockIdx.y * CPT;
    #pragma unroll
    for (int i = 0; i < CPT; ++i) {
        const int c = c0 + i;
        outb[(size_t)c * HW] = inb[(size_t)c * PIX] * w;
    }
}

extern "C" void kernel_launch(void* const* d_in, const int* in_sizes, int n_in,
                              void* d_out, int out_size, void* d_ws, size_t ws_size,
                              hipStream_t stream)
{
    const float* input   = (const float*)d_in[0];
    const int*   uu      = (const int*)  d_in[1];
    const int*   vv      = (const int*)  d_in[2];
    const float* valid   = (const float*)d_in[3];
    const float* density = (const float*)d_in[4];
    float*       out     = (float*)d_out;

    const size_t T_bytes = (size_t)PIX * ROWH * sizeof(__half);   // 31.5 MB
    if (ws_size >= T_bytes) {
        __half* T2 = (__half*)d_ws;
        transpose_f16_kernel<<<dim3(PIX / TA_P, C_IN / TA_C), dim3(256), 0, stream>>>(input, T2);
        gather_f16_kernel<<<dim3(LVOX / VB), dim3(256), 0, stream>>>(T2, uu, vv, valid, density, out);
    } else {
        voxel_proj_direct<<<dim3(LVOX / 256, C_IN / CPT), dim3(256), 0, stream>>>(
            input, uu, vv, valid, density, out);
    }
}